// Round 1
// baseline (877.707 us; speedup 1.0000x reference)
//
#include <hip/hip_runtime.h>
#include <hip/hip_bf16.h>

// DiagonalSSM: decays = sigmoid(X @ Wd^T + bd); inj = X @ Wi^T + bi;
// states[t] = decays[t]*states[t-1] + inj[t]  (per b, per d channel)
//
// Pipeline:
//   1) gemm_kernel: bf16x3-decomposed MFMA GEMM, M=32768, N=2048 (decay|inj), K=1024
//      writes decays -> ws, injections -> d_out (reused as scratch)
//   2) scan_phase1: per-chunk aggregates (prod a, local end state)
//   3) scan_phase2: scan across chunk aggregates -> per-chunk carry-in
//   4) scan_phase3: re-scan chunks from carry, overwrite d_out with states

#define D_MODEL 1024
#define BATCH   8
#define SEQ     4096
#define M_TOT   (BATCH * SEQ)     // 32768
#define N_TOT   (2 * D_MODEL)     // 2048
#define K_TOT   D_MODEL           // 1024

#define TM 128
#define TN 128
#define BK 32

#define NC  64                    // scan chunks along T
#define LCH (SEQ / NC)            // 64

using f32x4 = __attribute__((ext_vector_type(4))) float;
using s16x8 = __attribute__((ext_vector_type(8))) short;
using s16x4 = __attribute__((ext_vector_type(4))) short;

__device__ __forceinline__ short bf16_rne(float f) {
    union { float f; unsigned u; } v; v.f = f;
    unsigned r = v.u + 0x7fffu + ((v.u >> 16) & 1u);
    return (short)(r >> 16);
}
__device__ __forceinline__ float bf16_to_f32(short s) {
    union { float f; unsigned u; } v; v.u = ((unsigned)(unsigned short)s) << 16;
    return v.f;
}

// ---------------------------------------------------------------------------
// GEMM: C[m][n] = sum_k X[m][k] * W[n][k]  (both row-major, K contiguous)
// bf16x3 split: x = xh + xl, w = wh + wl; acc += xh*wh + xh*wl + xl*wh
// ---------------------------------------------------------------------------
__global__ __launch_bounds__(256) void gemm_kernel(
    const float* __restrict__ X,
    const float* __restrict__ Wd, const float* __restrict__ Wi,
    const float* __restrict__ bd, const float* __restrict__ bi,
    float* __restrict__ decays, float* __restrict__ inj)
{
    // 4 LDS tiles (A_hi, A_lo, B_hi, B_lo), each TM x BK bf16 = 8 KB -> 32 KB
    __shared__ short lds[4 * TM * BK];
    char* ldsc = (char*)lds;
    const int AHI = 0;
    const int ALO = 1 * TM * BK * 2;
    const int BHI = 2 * TM * BK * 2;
    const int BLO = 3 * TM * BK * 2;

    const int tid  = threadIdx.x;
    const int lane = tid & 63;
    const int w    = tid >> 6;          // wave id 0..3
    const int wm   = w >> 1;            // 0..1
    const int wn   = w & 1;             // 0..1
    const int m0   = blockIdx.y * TM;
    const int n0   = blockIdx.x * TN;
    const bool is_decay = (n0 < D_MODEL);
    const float* Wbase = is_decay ? (Wd + (size_t)n0 * K_TOT)
                                  : (Wi + (size_t)(n0 - D_MODEL) * K_TOT);

    const int r = lane & 15;            // fragment row/col within 16
    const int g = lane >> 4;            // k-group 0..3

    f32x4 acc[4][4];
    #pragma unroll
    for (int i = 0; i < 4; i++)
        #pragma unroll
        for (int j = 0; j < 4; j++)
            acc[i][j] = (f32x4){0.f, 0.f, 0.f, 0.f};

    for (int k0 = 0; k0 < K_TOT; k0 += BK) {
        __syncthreads();
        // ---- stage: 128x32 f32 of A and of B -> split into hi/lo bf16 tiles
        #pragma unroll
        for (int j = 0; j < 4; j++) {
            int i   = tid + j * 256;    // 0..1023
            int row = i >> 3;           // 0..127
            int c4  = i & 7;            // 0..7 (float4 within 32-float row)
            f32x4 av = *(const f32x4*)(X + (size_t)(m0 + row) * K_TOT + k0 + c4 * 4);
            f32x4 bv = *(const f32x4*)(Wbase + (size_t)row * K_TOT + k0 + c4 * 4);
            s16x4 ah, al, bh, bl;
            #pragma unroll
            for (int u = 0; u < 4; u++) {
                short h = bf16_rne(av[u]);
                ah[u] = h;
                al[u] = bf16_rne(av[u] - bf16_to_f32(h));
                short hb = bf16_rne(bv[u]);
                bh[u] = hb;
                bl[u] = bf16_rne(bv[u] - bf16_to_f32(hb));
            }
            int off = (row * (BK * 2) + c4 * 8) ^ ((row & 7) << 4);
            *(s16x4*)(ldsc + AHI + off) = ah;
            *(s16x4*)(ldsc + ALO + off) = al;
            *(s16x4*)(ldsc + BHI + off) = bh;
            *(s16x4*)(ldsc + BLO + off) = bl;
        }
        __syncthreads();

        // ---- fragments: lane holds A[row=r][k=g*8+j], B[k=g*8+j][col=r]
        s16x8 a_hi[4], a_lo[4], b_hi[4], b_lo[4];
        #pragma unroll
        for (int mi = 0; mi < 4; mi++) {
            int row = wm * 64 + mi * 16 + r;
            int off = (row * (BK * 2) + g * 16) ^ ((row & 7) << 4);
            a_hi[mi] = *(const s16x8*)(ldsc + AHI + off);
            a_lo[mi] = *(const s16x8*)(ldsc + ALO + off);
        }
        #pragma unroll
        for (int ni = 0; ni < 4; ni++) {
            int row = wn * 64 + ni * 16 + r;
            int off = (row * (BK * 2) + g * 16) ^ ((row & 7) << 4);
            b_hi[ni] = *(const s16x8*)(ldsc + BHI + off);
            b_lo[ni] = *(const s16x8*)(ldsc + BLO + off);
        }
        #pragma unroll
        for (int mi = 0; mi < 4; mi++)
            #pragma unroll
            for (int ni = 0; ni < 4; ni++) {
                acc[mi][ni] = __builtin_amdgcn_mfma_f32_16x16x32_bf16(a_hi[mi], b_hi[ni], acc[mi][ni], 0, 0, 0);
                acc[mi][ni] = __builtin_amdgcn_mfma_f32_16x16x32_bf16(a_hi[mi], b_lo[ni], acc[mi][ni], 0, 0, 0);
                acc[mi][ni] = __builtin_amdgcn_mfma_f32_16x16x32_bf16(a_lo[mi], b_hi[ni], acc[mi][ni], 0, 0, 0);
            }
    }

    // ---- epilogue: C row = (lane>>4)*4 + j, col = lane&15 (m89-verified)
    const float* bias_ptr = is_decay ? bd : bi;
    float* outp           = is_decay ? decays : inj;
    const int ncol_base   = is_decay ? n0 : (n0 - D_MODEL);
    #pragma unroll
    for (int mi = 0; mi < 4; mi++) {
        #pragma unroll
        for (int ni = 0; ni < 4; ni++) {
            int col = ncol_base + wn * 64 + ni * 16 + r;
            float bias = bias_ptr[col];
            #pragma unroll
            for (int j = 0; j < 4; j++) {
                int rowg = m0 + wm * 64 + mi * 16 + g * 4 + j;
                float v = acc[mi][ni][j] + bias;
                if (is_decay) v = 1.0f / (1.0f + __expf(-v));
                outp[(size_t)rowg * D_MODEL + col] = v;
            }
        }
    }
}

// ---------------------------------------------------------------------------
// Scan phase 1: per (b, chunk, d): p = prod(a), s = local scan end (zero init)
// ---------------------------------------------------------------------------
__global__ __launch_bounds__(256) void scan_phase1(
    const float* __restrict__ decays, const float* __restrict__ inj,
    float* __restrict__ P, float* __restrict__ E)
{
    const int d = blockIdx.x * 256 + threadIdx.x;
    const int b = blockIdx.y;
    const int c = blockIdx.z;
    const size_t base = ((size_t)b * SEQ + (size_t)c * LCH) * D_MODEL + d;
    const float* ad = decays + base;
    const float* xj = inj + base;

    float p = 1.f, s = 0.f;
    for (int t = 0; t < LCH; t += 8) {
        float av[8], xv[8];
        #pragma unroll
        for (int u = 0; u < 8; u++) {
            av[u] = ad[(size_t)(t + u) * D_MODEL];
            xv[u] = xj[(size_t)(t + u) * D_MODEL];
        }
        #pragma unroll
        for (int u = 0; u < 8; u++) {
            s = av[u] * s + xv[u];
            p *= av[u];
        }
    }
    const size_t idx = ((size_t)b * NC + c) * D_MODEL + d;
    P[idx] = p;
    E[idx] = s;
}

// ---------------------------------------------------------------------------
// Scan phase 2: per (b, d): carry[c] = state entering chunk c
// ---------------------------------------------------------------------------
__global__ __launch_bounds__(256) void scan_phase2(
    const float* __restrict__ P, const float* __restrict__ E,
    float* __restrict__ carry)
{
    const int d = blockIdx.x * 256 + threadIdx.x;
    const int b = blockIdx.y;
    float s = 0.f;
    for (int c = 0; c < NC; c++) {
        const size_t idx = ((size_t)b * NC + c) * D_MODEL + d;
        carry[idx] = s;
        s = P[idx] * s + E[idx];
    }
}

// ---------------------------------------------------------------------------
// Scan phase 3: re-scan each chunk from its carry; overwrite io with states
// ---------------------------------------------------------------------------
__global__ __launch_bounds__(256) void scan_phase3(
    const float* __restrict__ decays, float* __restrict__ io,
    const float* __restrict__ carry)
{
    const int d = blockIdx.x * 256 + threadIdx.x;
    const int b = blockIdx.y;
    const int c = blockIdx.z;
    const size_t base = ((size_t)b * SEQ + (size_t)c * LCH) * D_MODEL + d;
    const float* ad = decays + base;
    float* io_p = io + base;

    float s = carry[((size_t)b * NC + c) * D_MODEL + d];
    for (int t = 0; t < LCH; t += 8) {
        float av[8], xv[8], sv[8];
        #pragma unroll
        for (int u = 0; u < 8; u++) {
            av[u] = ad[(size_t)(t + u) * D_MODEL];
            xv[u] = io_p[(size_t)(t + u) * D_MODEL];
        }
        #pragma unroll
        for (int u = 0; u < 8; u++) {
            s = av[u] * s + xv[u];
            sv[u] = s;
        }
        #pragma unroll
        for (int u = 0; u < 8; u++) {
            io_p[(size_t)(t + u) * D_MODEL] = sv[u];
        }
    }
}

// ---------------------------------------------------------------------------
extern "C" void kernel_launch(void* const* d_in, const int* in_sizes, int n_in,
                              void* d_out, int out_size, void* d_ws, size_t ws_size,
                              hipStream_t stream)
{
    const float* X  = (const float*)d_in[0];
    const float* Wd = (const float*)d_in[1];
    const float* bd = (const float*)d_in[2];
    const float* Wi = (const float*)d_in[3];
    const float* bi = (const float*)d_in[4];
    float* out = (float*)d_out;

    char* ws = (char*)d_ws;
    float* decays = (float*)ws;                              // 128 MiB
    size_t dec_elems = (size_t)M_TOT * D_MODEL;
    float* P     = decays + dec_elems;                       // 2 MiB
    float* E     = P + (size_t)BATCH * NC * D_MODEL;         // 2 MiB
    float* carry = E + (size_t)BATCH * NC * D_MODEL;         // 2 MiB

    dim3 gg(N_TOT / TN, M_TOT / TM, 1);
    gemm_kernel<<<gg, 256, 0, stream>>>(X, Wd, Wi, bd, bi, decays, out);

    dim3 g1(D_MODEL / 256, BATCH, NC);
    scan_phase1<<<g1, 256, 0, stream>>>(decays, out, P, E);
    scan_phase2<<<dim3(D_MODEL / 256, BATCH, 1), 256, 0, stream>>>(P, E, carry);
    scan_phase3<<<g1, 256, 0, stream>>>(decays, out, carry);
}